// Round 7
// baseline (1221.906 us; speedup 1.0000x reference)
//
#include <hip/hip_runtime.h>
#include <cstdint>
#include <cstddef>

// ---------------------------------------------------------------------------
// Sizes: C=512,H=4,W=4,SPLIT=4,WC=1 -> L=2048, B=16, gates=4*L=8192
// 8 weight matrices [8192][2048] fp32 -> fp8 e4m3 (x64), fragment-packed:
// 512 ch-tiles x 64 k-steps x 512B (16x32 MFMA fragment, lane l -> 8B at l*8).
// Fragment map: A-row r -> weight row (r>>2)*2048 + bt*4 + (r&3);
//               k = ks*32 + (l>>4)*8 + j.   Activations same, col = batch n.
// Whole 15-step recurrence runs in ONE persistent kernel (512 blocks
// co-resident; device-scope software barriers between super-steps).
// ---------------------------------------------------------------------------

typedef __attribute__((ext_vector_type(8))) short short8;   // 8 x bf16
typedef __attribute__((ext_vector_type(4))) short short4v;
typedef __attribute__((ext_vector_type(4))) float f32x4;

#define NBATCH 16
#define MAT_B   16777216ull     // bytes per packed fp8 matrix (8192*2048)
#define WSCALE  64.0f
#define INVWS   (1.0f / 64.0f)
#define NBLK    512

__device__ __forceinline__ short f2bf(float f) {
    union { float f; unsigned u; } c; c.f = f;
    unsigned u = c.u;
    unsigned r = (u + 0x7FFFu + ((u >> 16) & 1u)) >> 16;
    return (short)r;
}

// HW packed fp8 quantize: 4 floats -> 4 OCP e4m3fn bytes (one dword)
__device__ __forceinline__ uint32_t f4_to_fp8x4(float a, float b, float c, float d) {
    int p = __builtin_amdgcn_cvt_pk_fp8_f32(a, b, 0, false);   // bytes 0,1
    p = __builtin_amdgcn_cvt_pk_fp8_f32(c, d, p, true);        // bytes 2,3
    return (uint32_t)p;
}

__device__ __forceinline__ uint8_t f2fp8hw(float x) {
    return (uint8_t)(__builtin_amdgcn_cvt_pk_fp8_f32(x, x, 0, false) & 0xFF);
}

__device__ __forceinline__ float sigmoidf_(float x) { return 1.f / (1.f + __expf(-x)); }

// packed byte offset for activation element (batch n, feature k)
__device__ __forceinline__ int apos(int n, int k) {
    return ((k >> 5) << 9) + ((((k >> 3) & 3) << 4) + n) * 8 + (k & 7);
}

// ---------------------------------------------------------------------------
// Device-scope grid barrier (one fresh counter per barrier; counters zeroed
// by k_init each call). Release/acquire at agent scope makes h/SA/midp
// written before the barrier visible across XCDs after it.
// ---------------------------------------------------------------------------
__device__ __forceinline__ void gbar(unsigned* bar, int idx) {
    __syncthreads();
    if (threadIdx.x == 0) {
        __builtin_amdgcn_fence(__ATOMIC_RELEASE, "agent");
        __hip_atomic_fetch_add(bar + idx, 1u, __ATOMIC_RELAXED, __HIP_MEMORY_SCOPE_AGENT);
        while (__hip_atomic_load(bar + idx, __ATOMIC_RELAXED, __HIP_MEMORY_SCOPE_AGENT) < NBLK)
            __builtin_amdgcn_s_sleep(1);
        __builtin_amdgcn_fence(__ATOMIC_ACQUIRE, "agent");
    }
    __syncthreads();
}

// ---------------------------------------------------------------------------
// Pack all 8 matrices fp32 -> fragment-ordered fp8 (x64), via LDS staging.
// ---------------------------------------------------------------------------
__global__ __launch_bounds__(256) void k_pack8(
    const float* __restrict__ enc_Wih, const float* __restrict__ enc_Whh,
    const float* __restrict__ dec_Wih, const float* __restrict__ dec_Whh,
    uint8_t* __restrict__ dstbase)
{
    __shared__ uint8_t lbuf[16 * 1032];

    const int blk  = blockIdx.x;
    const int om   = blk >> 10;
    const int mat  = (om + 4) & 7;              // dec (4..7) first, enc (0..3) last
    const int sub  = blk & 1023;
    const int bt   = sub >> 1;
    const int half = sub & 1;
    const int tid  = threadIdx.x;

    const float* srcs[4] = { enc_Wih, enc_Whh, dec_Wih, dec_Whh };
    const float* src = srcs[mat >> 1] + (size_t)(mat & 1) * 16777216ull;
    uint8_t* dst = dstbase + (size_t)mat * MAT_B
                 + (((size_t)bt * 64 + half * 32) << 9);

#pragma unroll 4
    for (int it = 0; it < 16; ++it) {
        int s  = it * 256 + tid;
        int rl = s >> 8;
        int c0 = (s & 255) * 4;
        int row = (rl >> 2) * 2048 + bt * 4 + (rl & 3);
        f32x4 v = __builtin_nontemporal_load(
            (const f32x4*)(src + (size_t)row * 2048 + half * 1024 + c0));
        uint32_t w32 = f4_to_fp8x4(v[0] * WSCALE, v[1] * WSCALE,
                                   v[2] * WSCALE, v[3] * WSCALE);
        *(uint32_t*)(lbuf + rl * 1032 + c0) = w32;
    }
    __syncthreads();

#pragma unroll 4
    for (int it = 0; it < 16; ++it) {
        int s    = it * 256 + tid;
        int fl   = s >> 7;
        int w    = s & 127;
        int lane = w >> 1;
        int j0   = (s & 1) * 4;
        int rl   = lane & 15;
        int c0   = fl * 32 + (lane >> 4) * 8 + j0;
        *(uint32_t*)(dst + (size_t)s * 4) = *(const uint32_t*)(lbuf + rl * 1032 + c0);
    }
}

// ---------------------------------------------------------------------------
// Pack conv weights [512][1024] fp32 -> bf16 fragments (32 mt-tiles)
// ---------------------------------------------------------------------------
__global__ __launch_bounds__(256) void k_packc(const float* __restrict__ Wc,
                                               short* __restrict__ Wcp)
{
    __shared__ short lb[16 * 1032];
    const int mt = blockIdx.x, tid = threadIdx.x;
#pragma unroll 4
    for (int it = 0; it < 16; ++it) {
        int s = it * 256 + tid;
        int rl = s >> 8;
        int c0 = (s & 255) * 4;
        f32x4 v = *(const f32x4*)(Wc + (size_t)(mt * 16 + rl) * 1024 + c0);
        short4v o;
        o[0] = f2bf(v[0]); o[1] = f2bf(v[1]); o[2] = f2bf(v[2]); o[3] = f2bf(v[3]);
        *(short4v*)(lb + rl * 1032 + c0) = o;
    }
    __syncthreads();
    short* dst = Wcp + (size_t)mt * 16384;
#pragma unroll 4
    for (int it = 0; it < 16; ++it) {
        int s    = it * 256 + tid;
        int fl   = s >> 7;
        int w    = s & 127;
        int lane = w >> 1;
        int j0   = (s & 1) * 4;
        int rl   = lane & 15;
        int c0   = fl * 32 + (lane >> 4) * 8 + j0;
        *(short4v*)(dst + (size_t)s * 4) = *(const short4v*)(lb + rl * 1032 + c0);
    }
}

// ---------------------------------------------------------------------------
// Init: zero h/c + barrier counters + pack inputs (fp8) + copies x1/x2 -> out
// ---------------------------------------------------------------------------
__global__ __launch_bounds__(256) void k_init(
    const float* __restrict__ x1, const float* __restrict__ x2,
    uint8_t* __restrict__ xc1, uint8_t* __restrict__ xc2,
    uint8_t* __restrict__ hbuf, float* __restrict__ cst,
    unsigned* __restrict__ bar, float* __restrict__ out)
{
    int i = blockIdx.x * blockDim.x + threadIdx.x;  // 131072 threads
    cst[i] = 0.f;
    if (i < 65536) { hbuf[i] = 0; hbuf[131072 + i] = 0; }
    if (i < 64) bar[i] = 0u;
    if (i < 32768) {
        int b = i >> 11, l = i & 2047;
        f32x4 v1 = ((const f32x4*)x1)[i];
        f32x4 v2 = ((const f32x4*)x2)[i];
        int p = apos(b, l);
        uint32_t q1 = f4_to_fp8x4(v1[0], v1[1], v1[2], v1[3]);
        uint32_t q2 = f4_to_fp8x4(v2[0], v2[1], v2[2], v2[3]);
#pragma unroll
        for (int s = 0; s < 4; ++s) {
            xc1[s * 32768 + p] = (uint8_t)(q1 >> (8 * s));
            xc2[s * 32768 + p] = (uint8_t)(q2 >> (8 * s));
        }
        ((f32x4*)(out + 131072))[i]     = v1;   // x1_parts[0] == x1
        ((f32x4*)(out + 6 * 131072))[i] = v2;   // x2_parts[2] == x2
    }
}

// ---------------------------------------------------------------------------
// Persistent sequence kernel context
// ---------------------------------------------------------------------------
struct Ctx {
    const uint8_t* Wb;
    const uint8_t* xc1;
    const uint8_t* xc2;
    uint8_t* hbuf;      // [layer][parity][branch][32768] fp8
    float*   cst;       // [layer][branch][16][2048] fp32
    float*   SA;        // 8 slots * 32768 fp32
    float*   SB;
    short*   midp;      // 16 nt * 16384 bf16 conv-B fragments
    const float* enc_bih; const float* enc_bhh;
    const float* dec_bih; const float* dec_bhh;
};

__device__ __forceinline__ uint8_t* hB(const Ctx& C, int layer, int par) {
    return C.hbuf + layer * 131072 + par * 65536;
}

// One LSTM cell unit (one layer, one step, both branches) for tile blockIdx.x
__device__ void cell_unit(const Ctx& C, int t, int layer,
                          float (*gpart)[2][16][17])
{
    const bool enc = (t <= 4);
    const int base = enc ? 0 : 4;
    const uint8_t* Wih = C.Wb + (size_t)(base + layer) * MAT_B;
    const uint8_t* Whh = C.Wb + (size_t)(base + 2 + layer) * MAT_B;
    const float* bih = (enc ? C.enc_bih : C.dec_bih) + layer * 8192;
    const float* bhh = (enc ? C.enc_bhh : C.dec_bhh) + layer * 8192;

    const uint8_t *xA, *xB, *hin;
    float* cstL; uint8_t* hout;
    float *svA = nullptr, *svB = nullptr; short* midp = nullptr; int slot = 0;
    if (layer == 0) {
        if (t <= 4)      { xA = C.xc2 + (size_t)(t - 1) * 32768; xB = C.xc1 + (size_t)(4 - t) * 32768; }
        else if (t <= 8) { xA = C.xc1 + (size_t)(t - 5) * 32768; xB = C.xc2 + (size_t)(8 - t) * 32768; }
        else             { const uint8_t* hp = hB(C, 1, (t - 1) & 1); xA = hp; xB = hp + 32768; }
        hin = hB(C, 0, (t - 1) & 1);
        cstL = C.cst;
        hout = hB(C, 0, t & 1);
    } else {
        const uint8_t* hx = hB(C, 0, t & 1);
        xA = hx; xB = hx + 32768;
        hin = hB(C, 1, (t - 1) & 1);
        cstL = C.cst + 65536;
        hout = hB(C, 1, t & 1);
        if (t >= 8) {
            svA = C.SA + (size_t)(t - 8) * 32768;
            svB = C.SB + (size_t)(t - 8) * 32768;
            slot = t - 8;
            if (t <= 11) midp = C.midp;
        }
    }

    const int bt   = blockIdx.x;
    const int tid  = threadIdx.x;
    const int w    = tid >> 6;
    const int lane = tid & 63;
    const int r    = lane & 15;
    const int g4   = lane >> 4;
    const int kq   = w & 3;

    const uint8_t* Wsrc = (w < 4) ? Wih : Whh;
    const uint8_t* uA   = (w < 4) ? xA : hin;
    const uint8_t* uB   = (w < 4) ? xB : (hin + 32768);

    const uint8_t* wp = Wsrc + (((size_t)bt * 64 + kq * 16) << 9) + lane * 8;
    const uint8_t* ap = uA + ((kq * 16) << 9) + lane * 8;
    const uint8_t* bp = uB + ((kq * 16) << 9) + lane * 8;

    __syncthreads();   // protect gpart reuse vs previous unit's epilogue

    long wreg[16];
#pragma unroll
    for (int i = 0; i < 16; ++i)
        wreg[i] = *(const long*)(wp + ((size_t)i << 9));

    f32x4 accA = {0.f, 0.f, 0.f, 0.f};
    f32x4 accB = {0.f, 0.f, 0.f, 0.f};
#pragma unroll
    for (int i = 0; i < 16; ++i) {
        long av = *(const long*)(ap + ((size_t)i << 9));
        long bv = *(const long*)(bp + ((size_t)i << 9));
        accA = __builtin_amdgcn_mfma_f32_16x16x32_fp8_fp8(wreg[i], av, accA, 0, 0, 0);
        accB = __builtin_amdgcn_mfma_f32_16x16x32_fp8_fp8(wreg[i], bv, accB, 0, 0, 0);
    }

#pragma unroll
    for (int q = 0; q < 4; ++q) {
        gpart[w][0][g4 * 4 + q][r] = accA[q];
        gpart[w][1][g4 * 4 + q][r] = accB[q];
    }
    __syncthreads();

    if (tid < 128) {
        const int br  = tid >> 6;
        const int chl = (tid >> 4) & 3;
        const int n   = tid & 15;

        float gi = 0.f, gf = 0.f, gg = 0.f, go = 0.f;
#pragma unroll
        for (int ww = 0; ww < 8; ++ww) {
            gi += gpart[ww][br][chl][n];
            gf += gpart[ww][br][4 + chl][n];
            gg += gpart[ww][br][8 + chl][n];
            go += gpart[ww][br][12 + chl][n];
        }
        const int ch = bt * 4 + chl;
        gi = gi * INVWS + bih[ch]            + bhh[ch];
        gf = gf * INVWS + bih[2048 + ch]     + bhh[2048 + ch];
        gg = gg * INVWS + bih[2 * 2048 + ch] + bhh[2 * 2048 + ch];
        go = go * INVWS + bih[3 * 2048 + ch] + bhh[3 * 2048 + ch];

        const size_t idx = ((size_t)br * NBATCH + n) * 2048 + ch;
        float cold = cstL[idx];
        float cn = sigmoidf_(gf) * cold + sigmoidf_(gi) * tanhf(gg);
        float hn = sigmoidf_(go) * tanhf(cn);
        cstL[idx] = cn;
        hout[br * 32768 + apos(n, ch)] = f2fp8hw(hn);
        if (br == 0) { if (svA) svA[(size_t)n * 2048 + ch] = hn; }
        else         { if (svB) svB[(size_t)n * 2048 + ch] = hn; }
        if (midp) {
            int i8, pos;
            if (br == 0) { i8 = ch >> 2;         pos = n * 16 + (ch & 3) * 4 + slot; }
            else         { i8 = 512 + (ch >> 2); pos = n * 16 + (ch & 3) * 4 + (3 - slot); }
            midp[(pos >> 4) * 16384 + (i8 >> 5) * 512
                 + (((i8 >> 3) & 3) * 16 + (pos & 15)) * 8 + (i8 & 7)] = f2bf(hn);
        }
    }
}

// ---------------------------------------------------------------------------
// Persistent kernel: all 30 cell units + out[2..5] scatter + 1x1 conv.
// 512 blocks x 512 threads; __launch_bounds__(512,4) -> 2 blocks/CU,
// 512 blocks == exactly co-resident on 256 CUs.
// ---------------------------------------------------------------------------
__global__ __launch_bounds__(512, 4) void k_seq(
    Ctx C, const short* __restrict__ Wcp, const float* __restrict__ conv_b,
    float* __restrict__ out, unsigned* __restrict__ bar)
{
    __shared__ float gpart[8][2][16][17];
    int nb = 0;

    cell_unit(C, 1, 0, gpart);
    gbar(bar, nb++);
    for (int t = 2; t <= 8; ++t) {
        cell_unit(C, t, 0, gpart);          // L0(t)
        cell_unit(C, t - 1, 1, gpart);      // || L1(t-1)  (inputs from < this super-step)
        gbar(bar, nb++);
    }
    cell_unit(C, 8, 1, gpart);
    gbar(bar, nb++);
    for (int t = 9; t <= 15; ++t) {
        cell_unit(C, t, 0, gpart);
        gbar(bar, nb++);
        cell_unit(C, t, 1, gpart);
        gbar(bar, nb++);
    }

    // ---- out[2..5] scatter (first 131072 threads) ----
    int gid = blockIdx.x * 512 + threadIdx.x;
    if (gid < 131072) {
        int q  = gid >> 15;
        int rr = gid & 32767;
        const float* base = (q < 2) ? C.SA : C.SB;
        int sl0 = (q == 0) ? 0 : (q == 1) ? 4 : (q == 2) ? 7 : 3;
        int stp = (q < 2) ? 1 : -1;
        f32x4 o;
#pragma unroll
        for (int w2 = 0; w2 < 4; ++w2)
            o[w2] = base[(size_t)(sl0 + stp * w2) * 32768 + rr];
        ((f32x4*)(out + (size_t)(2 + q) * 131072))[rr] = o;
    }

    // ---- 1x1 conv GEMM: block -> (mt, nt), first 256 threads ----
    __syncthreads();
    float (*gp)[16][17] = (float (*)[16][17])gpart;
    const int tid = threadIdx.x;
    const int mt = blockIdx.x >> 4, nt = blockIdx.x & 15;
    if (tid < 256) {
        const int kw = tid >> 6, lane = tid & 63;
        const short* ap = Wcp + (size_t)mt * 16384 + kw * 8 * 512 + lane * 8;
        const short* bp = C.midp + (size_t)nt * 16384 + kw * 8 * 512 + lane * 8;
        f32x4 acc = {0.f, 0.f, 0.f, 0.f};
#pragma unroll
        for (int i = 0; i < 8; ++i) {
            short8 a = *(const short8*)(ap + i * 512);
            short8 b = *(const short8*)(bp + i * 512);
            acc = __builtin_amdgcn_mfma_f32_16x16x32_bf16(a, b, acc, 0, 0, 0);
        }
        const int r = lane & 15, g4 = lane >> 4;
#pragma unroll
        for (int q = 0; q < 4; ++q) gp[kw][g4 * 4 + q][r] = acc[q];
    }
    __syncthreads();
    if (tid < 256) {
        const int m = tid >> 4, nl = tid & 15;
        float s = gp[0][m][nl] + gp[1][m][nl] + gp[2][m][nl] + gp[3][m][nl];
        const int o = mt * 16 + m, pos = nt * 16 + nl;
        s += conv_b[o];
        s = s > 0.f ? s : 0.2f * s;
        const int b = pos >> 4, hp = (pos >> 2) & 3, w = pos & 3;
        out[(size_t)b * 8192 + o * 16 + hp * 4 + w] = s;
    }
}

__global__ void k_wsfail(float* out) { if (threadIdx.x == 0 && blockIdx.x == 0) out[0] = -7.7e7f; }

// ---------------------------------------------------------------------------
extern "C" void kernel_launch(void* const* d_in, const int* in_sizes, int n_in,
                              void* d_out, int out_size, void* d_ws, size_t ws_size,
                              hipStream_t stream)
{
    const float* x1      = (const float*)d_in[0];
    const float* x2      = (const float*)d_in[1];
    const float* enc_Wih = (const float*)d_in[2];
    const float* enc_Whh = (const float*)d_in[3];
    const float* enc_bih = (const float*)d_in[4];
    const float* enc_bhh = (const float*)d_in[5];
    const float* dec_Wih = (const float*)d_in[6];
    const float* dec_Whh = (const float*)d_in[7];
    const float* dec_bih = (const float*)d_in[8];
    const float* dec_bhh = (const float*)d_in[9];
    const float* conv_W  = (const float*)d_in[10];
    const float* conv_b  = (const float*)d_in[11];
    float* out = (float*)d_out;

    // workspace (mats 0..3 = enc{ihL0,ihL1,hhL0,hhL1}, 4..7 = dec)
    uint8_t* Wb   = (uint8_t*)d_ws;            // 8 * MAT_B fp8
    uint8_t* xc1  = Wb + 8 * MAT_B;            // 4 chunks * 32768 B
    uint8_t* xc2  = xc1 + 131072;
    uint8_t* hbuf = xc2 + 131072;              // [2][2][2][32768] fp8
    float*   cst  = (float*)(hbuf + 262144);   // [2][2][16][2048] fp32
    float*   SA   = cst + 131072;              // 8 slots * 32768 fp32
    float*   SB   = SA + 262144;
    short*   midp = (short*)(SB + 262144);     // 16 nt * 16384 bf16
    short*   Wcp  = midp + 262144;             // 32 mt * 16384 bf16
    unsigned* bar = (unsigned*)(Wcp + 524288); // 64 barrier counters
    size_t need = (size_t)((char*)(bar + 64) - (char*)d_ws);
    if (ws_size < need) { k_wsfail<<<1, 64, 0, stream>>>(out); return; }

    k_init<<<512, 256, 0, stream>>>(x1, x2, xc1, xc2, hbuf, cst, bar, out);
    k_pack8<<<8192, 256, 0, stream>>>(enc_Wih, enc_Whh, dec_Wih, dec_Whh, Wb);
    k_packc<<<32, 256, 0, stream>>>(conv_W, Wcp);

    Ctx C;
    C.Wb = Wb; C.xc1 = xc1; C.xc2 = xc2; C.hbuf = hbuf; C.cst = cst;
    C.SA = SA; C.SB = SB; C.midp = midp;
    C.enc_bih = enc_bih; C.enc_bhh = enc_bhh;
    C.dec_bih = dec_bih; C.dec_bhh = dec_bhh;

    k_seq<<<NBLK, 512, 0, stream>>>(C, Wcp, conv_b, out, bar);
}

// Round 8
// 372.678 us; speedup vs baseline: 3.2787x; 3.2787x over previous
//
#include <hip/hip_runtime.h>
#include <cstdint>
#include <cstddef>

// ---------------------------------------------------------------------------
// Sizes: C=512,H=4,W=4,SPLIT=4,WC=1 -> L=2048, B=16, gates=4*L=8192
// 8 weight matrices of [8192][2048] fp32 -> fp8 e4m3 (x64 scale), packed as
// 512 ch-tiles x 64 k-steps, each a 16x32 fragment in MFMA lane order
// (lane l holds 8 bytes at frag*512 + l*8).
// Fragment map: A-row r -> weight row (r>>2)*2048 + bt*4 + (r&3);
//               k = ks*32 + (l>>4)*8 + j.
// Activations: same per-fragment packing (fp8, unscaled), col = batch n.
// Gate epilogue multiplies the MFMA sum by 1/64.
// fp8 quantize uses HW v_cvt_pk_fp8_f32 (OCP e4m3fn on gfx950, RNE+sat).
// NOTE (round 7 lesson): persistent kernel + device-scope barriers = 3.2x
// regression (agent fences flush per-XCD L2 every step). Multi-launch graph
// replay (~1-2us/node) is the right structure here.
// ---------------------------------------------------------------------------

typedef __attribute__((ext_vector_type(8))) short short8;   // 8 x bf16
typedef __attribute__((ext_vector_type(4))) short short4v;
typedef __attribute__((ext_vector_type(4))) float f32x4;

#define NBATCH 16
#define MAT_B   16777216ull     // bytes per packed fp8 matrix (8192*2048)
#define WSCALE  64.0f
#define INVWS   (1.0f / 64.0f)

__device__ __forceinline__ short f2bf(float f) {
    union { float f; unsigned u; } c; c.f = f;
    unsigned u = c.u;
    unsigned r = (u + 0x7FFFu + ((u >> 16) & 1u)) >> 16;
    return (short)r;
}

// HW packed fp8 quantize: 4 floats -> 4 OCP e4m3fn bytes (one dword)
__device__ __forceinline__ uint32_t f4_to_fp8x4(float a, float b, float c, float d) {
    int p = __builtin_amdgcn_cvt_pk_fp8_f32(a, b, 0, false);   // bytes 0,1
    p = __builtin_amdgcn_cvt_pk_fp8_f32(c, d, p, true);        // bytes 2,3
    return (uint32_t)p;
}

__device__ __forceinline__ uint8_t f2fp8hw(float x) {
    return (uint8_t)(__builtin_amdgcn_cvt_pk_fp8_f32(x, x, 0, false) & 0xFF);
}

__device__ __forceinline__ float sigmoidf_(float x) { return 1.f / (1.f + __expf(-x)); }

// packed byte offset for activation element (batch n, feature k)
__device__ __forceinline__ int apos(int n, int k) {
    return ((k >> 5) << 9) + ((((k >> 3) & 3) << 4) + n) * 8 + (k & 7);
}

// ---------------------------------------------------------------------------
// Pack all 8 matrices fp32 -> fragment-ordered fp8 (x64), via LDS staging.
// Grid 8192: block -> (om, bt, half); om 0..3 = dec (packed first), 4..7 enc
// (enc written last -> freshest in L3 for steps 1-4).
// ---------------------------------------------------------------------------
__global__ __launch_bounds__(256) void k_pack8(
    const float* __restrict__ enc_Wih, const float* __restrict__ enc_Whh,
    const float* __restrict__ dec_Wih, const float* __restrict__ dec_Whh,
    uint8_t* __restrict__ dstbase)
{
    __shared__ uint8_t lbuf[16 * 1032];

    const int blk  = blockIdx.x;
    const int om   = blk >> 10;
    const int mat  = (om + 4) & 7;              // dec (4..7) first, enc (0..3) last
    const int sub  = blk & 1023;
    const int bt   = sub >> 1;
    const int half = sub & 1;
    const int tid  = threadIdx.x;

    const float* srcs[4] = { enc_Wih, enc_Whh, dec_Wih, dec_Whh };
    const float* src = srcs[mat >> 1] + (size_t)(mat & 1) * 16777216ull;
    uint8_t* dst = dstbase + (size_t)mat * MAT_B
                 + (((size_t)bt * 64 + half * 32) << 9);

    // phase 1: coalesced row reads -> fp8 LDS tile [16][1024] (+8 pad)
#pragma unroll 4
    for (int it = 0; it < 16; ++it) {
        int s  = it * 256 + tid;                // 0..4095
        int rl = s >> 8;
        int c0 = (s & 255) * 4;
        int row = (rl >> 2) * 2048 + bt * 4 + (rl & 3);
        f32x4 v = __builtin_nontemporal_load(
            (const f32x4*)(src + (size_t)row * 2048 + half * 1024 + c0));
        uint32_t w32 = f4_to_fp8x4(v[0] * WSCALE, v[1] * WSCALE,
                                   v[2] * WSCALE, v[3] * WSCALE);
        *(uint32_t*)(lbuf + rl * 1032 + c0) = w32;
    }
    __syncthreads();

    // phase 2: fragment-order linear writes (16 KB per block)
#pragma unroll 4
    for (int it = 0; it < 16; ++it) {
        int s    = it * 256 + tid;              // 0..4095, 4 bytes each
        int fl   = s >> 7;                      // frag-local 0..31
        int w    = s & 127;
        int lane = w >> 1;
        int j0   = (s & 1) * 4;
        int rl   = lane & 15;
        int c0   = fl * 32 + (lane >> 4) * 8 + j0;
        *(uint32_t*)(dst + (size_t)s * 4) = *(const uint32_t*)(lbuf + rl * 1032 + c0);
    }
}

// ---------------------------------------------------------------------------
// Init (+ conv-weight pack, merged): blocks [0,512) zero h/c, pack inputs
// (fp8), copy x1->out[1] / x2->out[6]; blocks [512,544) pack conv weights
// [512][1024] fp32 -> bf16 fragments (32 mt-tiles).
// ---------------------------------------------------------------------------
__global__ __launch_bounds__(256) void k_init2(
    const float* __restrict__ x1, const float* __restrict__ x2,
    uint8_t* __restrict__ xc1, uint8_t* __restrict__ xc2,
    uint8_t* __restrict__ hbuf, float* __restrict__ cst,
    const float* __restrict__ Wc, short* __restrict__ Wcp,
    float* __restrict__ out)
{
    __shared__ short lb[16 * 1032];
    const int tid = threadIdx.x;

    if (blockIdx.x < 512) {
        int i = blockIdx.x * 256 + tid;             // 131072 threads
        cst[i] = 0.f;
        if (i < 65536) { hbuf[i] = 0; hbuf[131072 + i] = 0; }
        if (i < 32768) {
            int b = i >> 11, l = i & 2047;
            f32x4 v1 = ((const f32x4*)x1)[i];
            f32x4 v2 = ((const f32x4*)x2)[i];
            int p = apos(b, l);
            uint32_t q1 = f4_to_fp8x4(v1[0], v1[1], v1[2], v1[3]);
            uint32_t q2 = f4_to_fp8x4(v2[0], v2[1], v2[2], v2[3]);
#pragma unroll
            for (int s = 0; s < 4; ++s) {
                xc1[s * 32768 + p] = (uint8_t)(q1 >> (8 * s));
                xc2[s * 32768 + p] = (uint8_t)(q2 >> (8 * s));
            }
            ((f32x4*)(out + 131072))[i]     = v1;   // x1_parts[0] == x1
            ((f32x4*)(out + 6 * 131072))[i] = v2;   // x2_parts[2] == x2
        }
        return;
    }

    // conv-weight pack
    const int mt = blockIdx.x - 512;                // 0..31
#pragma unroll 4
    for (int it = 0; it < 16; ++it) {
        int s = it * 256 + tid;                     // 0..4095
        int rl = s >> 8;
        int c0 = (s & 255) * 4;
        f32x4 v = *(const f32x4*)(Wc + (size_t)(mt * 16 + rl) * 1024 + c0);
        short4v o;
        o[0] = f2bf(v[0]); o[1] = f2bf(v[1]); o[2] = f2bf(v[2]); o[3] = f2bf(v[3]);
        *(short4v*)(lb + rl * 1032 + c0) = o;
    }
    __syncthreads();
    short* dst = Wcp + (size_t)mt * 16384;
#pragma unroll 4
    for (int it = 0; it < 16; ++it) {
        int s    = it * 256 + tid;                  // 4 shorts each
        int fl   = s >> 7;
        int w    = s & 127;
        int lane = w >> 1;
        int j0   = (s & 1) * 4;
        int rl   = lane & 15;
        int c0   = fl * 32 + (lane >> 4) * 8 + j0;
        *(short4v*)(dst + (size_t)s * 4) = *(const short4v*)(lb + rl * 1032 + c0);
    }
}

// ---------------------------------------------------------------------------
// LSTM cell (fp8), both branches. Dual-job: blocks [0,512)=jA, [512,1024)=jB.
// Block owns 4 channels; 8 waves split K (4x Wih quarters, 4x Whh quarters).
// ---------------------------------------------------------------------------
struct CellJob {
    const uint8_t *Wih, *Whh;      // packed fp8 [512][64][512B]
    const float *bih, *bhh;        // [8192] fp32
    const uint8_t *xA, *xB, *hin;  // packed fp8 acts (hin: 2 branches x 32768B)
    float *cst;                    // [2][16][2048] fp32 in-place
    uint8_t *hout;                 // packed fp8 [2][32768]
    float *svA, *svB;              // optional fp32 [16][2048]
    short *midp;                   // optional bf16 conv-B fragments
    int slot;
};

__global__ __launch_bounds__(512, 4) void k_cell(CellJob jA, CellJob jB)
{
    __shared__ float gpart[8][2][16][17];

    const CellJob& J = (blockIdx.x < 512) ? jA : jB;
    const int bt   = blockIdx.x & 511;
    const int tid  = threadIdx.x;
    const int w    = tid >> 6;
    const int lane = tid & 63;
    const int r    = lane & 15;
    const int g4   = lane >> 4;
    const int kq   = w & 3;

    const uint8_t* Wsrc = (w < 4) ? J.Wih : J.Whh;
    const uint8_t* uA   = (w < 4) ? J.xA : J.hin;
    const uint8_t* uB   = (w < 4) ? J.xB : (J.hin + 32768);

    const uint8_t* wp = Wsrc + (((size_t)bt * 64 + kq * 16) << 9) + lane * 8;
    const uint8_t* ap = uA + ((kq * 16) << 9) + lane * 8;
    const uint8_t* bp = uB + ((kq * 16) << 9) + lane * 8;

    long wreg[16];
#pragma unroll
    for (int i = 0; i < 16; ++i)
        wreg[i] = *(const long*)(wp + ((size_t)i << 9));

    f32x4 accA = {0.f, 0.f, 0.f, 0.f};
    f32x4 accB = {0.f, 0.f, 0.f, 0.f};
#pragma unroll
    for (int i = 0; i < 16; ++i) {
        long av = *(const long*)(ap + ((size_t)i << 9));
        long bv = *(const long*)(bp + ((size_t)i << 9));
        accA = __builtin_amdgcn_mfma_f32_16x16x32_fp8_fp8(wreg[i], av, accA, 0, 0, 0);
        accB = __builtin_amdgcn_mfma_f32_16x16x32_fp8_fp8(wreg[i], bv, accB, 0, 0, 0);
    }

    // C layout: col = lane&15, row m = g4*4+q  (m -> gate m>>2, chl m&3)
#pragma unroll
    for (int q = 0; q < 4; ++q) {
        gpart[w][0][g4 * 4 + q][r] = accA[q];
        gpart[w][1][g4 * 4 + q][r] = accB[q];
    }
    __syncthreads();

    if (tid < 128) {
        const int br  = tid >> 6;
        const int chl = (tid >> 4) & 3;
        const int n   = tid & 15;

        float gi = 0.f, gf = 0.f, gg = 0.f, go = 0.f;
#pragma unroll
        for (int ww = 0; ww < 8; ++ww) {
            gi += gpart[ww][br][chl][n];
            gf += gpart[ww][br][4 + chl][n];
            gg += gpart[ww][br][8 + chl][n];
            go += gpart[ww][br][12 + chl][n];
        }
        const int ch = bt * 4 + chl;
        gi = gi * INVWS + J.bih[ch]            + J.bhh[ch];
        gf = gf * INVWS + J.bih[2048 + ch]     + J.bhh[2048 + ch];
        gg = gg * INVWS + J.bih[2 * 2048 + ch] + J.bhh[2 * 2048 + ch];
        go = go * INVWS + J.bih[3 * 2048 + ch] + J.bhh[3 * 2048 + ch];

        const size_t idx = ((size_t)br * NBATCH + n) * 2048 + ch;
        float cold = J.cst[idx];
        float cn = sigmoidf_(gf) * cold + sigmoidf_(gi) * tanhf(gg);
        float hn = sigmoidf_(go) * tanhf(cn);
        J.cst[idx] = cn;
        J.hout[br * 32768 + apos(n, ch)] = f2fp8hw(hn);
        if (br == 0) { if (J.svA) J.svA[(size_t)n * 2048 + ch] = hn; }
        else         { if (J.svB) J.svB[(size_t)n * 2048 + ch] = hn; }
        if (J.midp) {
            int i8, pos;
            if (br == 0) { i8 = ch >> 2;         pos = n * 16 + (ch & 3) * 4 + J.slot; }
            else         { i8 = 512 + (ch >> 2); pos = n * 16 + (ch & 3) * 4 + (3 - J.slot); }
            J.midp[(pos >> 4) * 16384 + (i8 >> 5) * 512
                   + (((i8 >> 3) & 3) * 16 + (pos & 15)) * 8 + (i8 & 7)] = f2bf(hn);
        }
    }
}

// ---------------------------------------------------------------------------
// Finish (merged): blocks [0,256) = out[2..5] scatter (coalesced both sides);
// blocks [256,768) = 1x1 conv as packed MFMA GEMM (mt,nt), 4 waves on K=1024.
// out2=[de1,p1,p2,p3]=SA[w]; out3=SA[4+w]; out4=SB[7-w]; out5=SB[3-w]
// ---------------------------------------------------------------------------
__global__ __launch_bounds__(512) void k_fin2(
    const short* __restrict__ Wcp, const short* __restrict__ midp,
    const float* __restrict__ bc,
    const float* __restrict__ SA, const float* __restrict__ SB,
    float* __restrict__ out)
{
    __shared__ float gp[4][16][17];
    const int tid = threadIdx.x;

    if (blockIdx.x < 256) {
        int i  = blockIdx.x * 512 + tid;       // 0..131071
        int q  = i >> 15;
        int rr = i & 32767;
        const float* base = (q < 2) ? SA : SB;
        int sl0 = (q == 0) ? 0 : (q == 1) ? 4 : (q == 2) ? 7 : 3;
        int stp = (q < 2) ? 1 : -1;
        f32x4 o;
#pragma unroll
        for (int w2 = 0; w2 < 4; ++w2)
            o[w2] = base[(size_t)(sl0 + stp * w2) * 32768 + rr];
        ((f32x4*)(out + (size_t)(2 + q) * 131072))[rr] = o;
        return;
    }

    const int blk2 = blockIdx.x - 256;         // 0..511
    const int mt = blk2 >> 4, nt = blk2 & 15;
    if (tid < 256) {
        const int kw = tid >> 6, lane = tid & 63;
        const short* ap = Wcp + (size_t)mt * 16384 + kw * 8 * 512 + lane * 8;
        const short* bp = midp + (size_t)nt * 16384 + kw * 8 * 512 + lane * 8;
        f32x4 acc = {0.f, 0.f, 0.f, 0.f};
#pragma unroll
        for (int i = 0; i < 8; ++i) {
            short8 a = *(const short8*)(ap + i * 512);
            short8 b = *(const short8*)(bp + i * 512);
            acc = __builtin_amdgcn_mfma_f32_16x16x32_bf16(a, b, acc, 0, 0, 0);
        }
        const int r = lane & 15, g4 = lane >> 4;
#pragma unroll
        for (int q = 0; q < 4; ++q) gp[kw][g4 * 4 + q][r] = acc[q];
    }
    __syncthreads();
    if (tid < 256) {
        const int m = tid >> 4, nl = tid & 15;
        float s = gp[0][m][nl] + gp[1][m][nl] + gp[2][m][nl] + gp[3][m][nl];
        const int o = mt * 16 + m, pos = nt * 16 + nl;
        s += bc[o];
        s = s > 0.f ? s : 0.2f * s;
        const int b = pos >> 4, hp = (pos >> 2) & 3, w = pos & 3;
        out[(size_t)b * 8192 + o * 16 + hp * 4 + w] = s;
    }
}

__global__ void k_wsfail(float* out) { if (threadIdx.x == 0 && blockIdx.x == 0) out[0] = -7.7e7f; }

// ---------------------------------------------------------------------------
extern "C" void kernel_launch(void* const* d_in, const int* in_sizes, int n_in,
                              void* d_out, int out_size, void* d_ws, size_t ws_size,
                              hipStream_t stream)
{
    const float* x1      = (const float*)d_in[0];
    const float* x2      = (const float*)d_in[1];
    const float* enc_Wih = (const float*)d_in[2];
    const float* enc_Whh = (const float*)d_in[3];
    const float* enc_bih = (const float*)d_in[4];
    const float* enc_bhh = (const float*)d_in[5];
    const float* dec_Wih = (const float*)d_in[6];
    const float* dec_Whh = (const float*)d_in[7];
    const float* dec_bih = (const float*)d_in[8];
    const float* dec_bhh = (const float*)d_in[9];
    const float* conv_W  = (const float*)d_in[10];
    const float* conv_b  = (const float*)d_in[11];
    float* out = (float*)d_out;

    // workspace (mats 0..3 = enc{ihL0,ihL1,hhL0,hhL1}, 4..7 = dec)
    uint8_t* Wb   = (uint8_t*)d_ws;            // 8 * MAT_B fp8
    uint8_t* xc1  = Wb + 8 * MAT_B;            // 4 chunks * 32768 B
    uint8_t* xc2  = xc1 + 131072;
    uint8_t* hbuf = xc2 + 131072;              // [2][2][2][32768] fp8
    float*   cst  = (float*)(hbuf + 262144);   // [2][2][16][2048] fp32
    float*   SA   = cst + 131072;              // 8 slots * 32768 fp32
    float*   SB   = SA + 262144;
    short*   midp = (short*)(SB + 262144);     // 16 nt * 16384 bf16
    short*   Wcp  = midp + 262144;             // 32 mt * 16384 bf16
    size_t need = (size_t)((char*)(Wcp + 524288) - (char*)d_ws);
    if (ws_size < need) { k_wsfail<<<1, 64, 0, stream>>>(out); return; }

    k_init2<<<544, 256, 0, stream>>>(x1, x2, xc1, xc2, hbuf, cst, conv_W, Wcp, out);
    k_pack8<<<8192, 256, 0, stream>>>(enc_Wih, enc_Whh, dec_Wih, dec_Whh, Wb);

    auto hB = [&](int layer, int par) -> uint8_t* {
        return hbuf + layer * 131072 + par * 65536;
    };

    auto mkJob = [&](int t, int layer) -> CellJob {
        const bool enc = (t <= 4);
        CellJob j;
        int base = enc ? 0 : 4;
        j.Wih = Wb + (size_t)(base + layer) * MAT_B;
        j.Whh = Wb + (size_t)(base + 2 + layer) * MAT_B;
        j.bih = (enc ? enc_bih : dec_bih) + layer * 8192;
        j.bhh = (enc ? enc_bhh : dec_bhh) + layer * 8192;
        if (layer == 0) {
            if (t <= 4)      { j.xA = xc2 + (size_t)(t - 1) * 32768; j.xB = xc1 + (size_t)(4 - t) * 32768; }
            else if (t <= 8) { j.xA = xc1 + (size_t)(t - 5) * 32768; j.xB = xc2 + (size_t)(8 - t) * 32768; }
            else             { const uint8_t* hp = hB(1, (t - 1) & 1); j.xA = hp; j.xB = hp + 32768; }
            j.hin = hB(0, (t - 1) & 1);
            j.cst = cst;
            j.hout = hB(0, t & 1);
            j.svA = nullptr; j.svB = nullptr; j.midp = nullptr; j.slot = 0;
        } else {
            const uint8_t* hx = hB(0, t & 1);
            j.xA = hx; j.xB = hx + 32768;
            j.hin = hB(1, (t - 1) & 1);
            j.cst = cst + 65536;
            j.hout = hB(1, t & 1);
            j.svA = (t >= 8) ? SA + (size_t)(t - 8) * 32768 : nullptr;
            j.svB = (t >= 8) ? SB + (size_t)(t - 8) * 32768 : nullptr;
            j.midp = (t >= 8 && t <= 11) ? midp : nullptr;
            j.slot = (t >= 8) ? (t - 8) : 0;
        }
        return j;
    };

    // t=1 layer0 alone
    k_cell<<<512, 512, 0, stream>>>(mkJob(1, 0), mkJob(1, 0));
    // t=2..8: layer0(t) || layer1(t-1)  (independent)
    for (int t = 2; t <= 8; ++t)
        k_cell<<<1024, 512, 0, stream>>>(mkJob(t, 0), mkJob(t - 1, 1));
    // layer1(8) alone
    k_cell<<<512, 512, 0, stream>>>(mkJob(8, 1), mkJob(8, 1));
    // AR steps: strictly serial
    for (int t = 9; t <= 15; ++t) {
        k_cell<<<512, 512, 0, stream>>>(mkJob(t, 0), mkJob(t, 0));
        k_cell<<<512, 512, 0, stream>>>(mkJob(t, 1), mkJob(t, 1));
    }

    k_fin2<<<768, 512, 0, stream>>>(Wcp, midp, conv_b, SA, SB, out);
}

// Round 9
// 365.705 us; speedup vs baseline: 3.3412x; 1.0191x over previous
//
#include <hip/hip_runtime.h>
#include <cstdint>
#include <cstddef>

// ---------------------------------------------------------------------------
// Sizes: C=512,H=4,W=4,SPLIT=4,WC=1 -> L=2048, B=16, gates=4*L=8192
// 8 weight matrices of [8192][2048] fp32 -> fp8 e4m3 (x64 scale), packed as
// 512 ch-tiles x 64 k-steps, each a 16x32 fragment in MFMA lane order
// (lane l holds 8 bytes at frag*512 + l*8).
// Fragment map: A-row r -> weight row (r>>2)*2048 + bt*4 + (r&3);
//               k = ks*32 + (l>>4)*8 + j.
// Activations: same per-fragment packing (fp8, unscaled), col = batch n.
// Gate epilogue multiplies the MFMA sum by 1/64.
// fp8 quantize uses HW v_cvt_pk_fp8_f32 (OCP e4m3fn on gfx950, RNE+sat).
// Round 7 lesson: persistent kernel + device barriers = 3.2x regression.
// Round 9: pack/init/packc merged into one dispatch; 16B phase-2 stores;
// zero-skip flags for t=1 cells (h=0, c=0 -> skip Whh reads + cst read,
// exact zeros so bit-identical); no zero-init pass needed at all.
// ---------------------------------------------------------------------------

typedef __attribute__((ext_vector_type(8))) short short8;   // 8 x bf16
typedef __attribute__((ext_vector_type(4))) short short4v;
typedef __attribute__((ext_vector_type(4))) float f32x4;
typedef __attribute__((ext_vector_type(2))) unsigned long long u64x2;

#define NBATCH 16
#define MAT_B   16777216ull     // bytes per packed fp8 matrix (8192*2048)
#define WSCALE  64.0f
#define INVWS   (1.0f / 64.0f)

__device__ __forceinline__ short f2bf(float f) {
    union { float f; unsigned u; } c; c.f = f;
    unsigned u = c.u;
    unsigned r = (u + 0x7FFFu + ((u >> 16) & 1u)) >> 16;
    return (short)r;
}

// HW packed fp8 quantize: 4 floats -> 4 OCP e4m3fn bytes (one dword)
__device__ __forceinline__ uint32_t f4_to_fp8x4(float a, float b, float c, float d) {
    int p = __builtin_amdgcn_cvt_pk_fp8_f32(a, b, 0, false);   // bytes 0,1
    p = __builtin_amdgcn_cvt_pk_fp8_f32(c, d, p, true);        // bytes 2,3
    return (uint32_t)p;
}

__device__ __forceinline__ uint8_t f2fp8hw(float x) {
    return (uint8_t)(__builtin_amdgcn_cvt_pk_fp8_f32(x, x, 0, false) & 0xFF);
}

__device__ __forceinline__ float sigmoidf_(float x) { return 1.f / (1.f + __expf(-x)); }

// packed byte offset for activation element (batch n, feature k)
__device__ __forceinline__ int apos(int n, int k) {
    return ((k >> 5) << 9) + ((((k >> 3) & 3) << 4) + n) * 8 + (k & 7);
}

// ---------------------------------------------------------------------------
// Merged prep dispatch, grid 8384:
//   blocks [0,8192):    pack 8 weight matrices fp32 -> fragment fp8 (x64)
//   blocks [8192,8320): input pack (fp8) + verbatim copies x1->out1, x2->out6
//   blocks [8320,8384): conv-weight pack fp32 -> bf16 fragments (half-tiles)
// ---------------------------------------------------------------------------
__global__ __launch_bounds__(256) void k_pack8i(
    const float* __restrict__ enc_Wih, const float* __restrict__ enc_Whh,
    const float* __restrict__ dec_Wih, const float* __restrict__ dec_Whh,
    uint8_t* __restrict__ dstbase,
    const float* __restrict__ x1, const float* __restrict__ x2,
    uint8_t* __restrict__ xc1, uint8_t* __restrict__ xc2,
    const float* __restrict__ Wc, short* __restrict__ Wcp,
    float* __restrict__ out)
{
    __shared__ uint8_t lbuf[16 * 1040];         // 16.6 KB, shared by all roles
    const int blk = blockIdx.x;
    const int tid = threadIdx.x;

    if (blk < 8192) {
        // ---- weight pack: (om, bt, half); om 0..3 = dec first, enc last ----
        const int om   = blk >> 10;
        const int mat  = (om + 4) & 7;          // dec (4..7) first, enc (0..3) last
        const int sub  = blk & 1023;
        const int bt   = sub >> 1;
        const int half = sub & 1;

        const float* srcs[4] = { enc_Wih, enc_Whh, dec_Wih, dec_Whh };
        const float* src = srcs[mat >> 1] + (size_t)(mat & 1) * 16777216ull;
        uint8_t* dst = dstbase + (size_t)mat * MAT_B
                     + (((size_t)bt * 64 + half * 32) << 9);

        // phase 1: coalesced row reads -> fp8 LDS tile [16][1024] (+8 pad)
#pragma unroll 4
        for (int it = 0; it < 16; ++it) {
            int s  = it * 256 + tid;            // 0..4095
            int rl = s >> 8;
            int c0 = (s & 255) * 4;
            int row = (rl >> 2) * 2048 + bt * 4 + (rl & 3);
            f32x4 v = __builtin_nontemporal_load(
                (const f32x4*)(src + (size_t)row * 2048 + half * 1024 + c0));
            uint32_t w32 = f4_to_fp8x4(v[0] * WSCALE, v[1] * WSCALE,
                                       v[2] * WSCALE, v[3] * WSCALE);
            *(uint32_t*)(lbuf + rl * 1032 + c0) = w32;
        }
        __syncthreads();

        // phase 2: fragment-order linear writes, 16 B per thread-iter.
        // dst bytes [s*16, s*16+16) = frag fl = s>>5, lanes 2m,2m+1 (m=s&31):
        // rows (2m)&15 and +1, cols fl*32 + (m>>3)*8 .. +8 each.
#pragma unroll
        for (int it = 0; it < 4; ++it) {
            int s  = it * 256 + tid;            // 0..1023
            int fl = s >> 5;
            int m  = s & 31;
            const uint8_t* p0 = lbuf + ((2 * m) & 15) * 1032 + fl * 32 + (m >> 3) * 8;
            u64x2 v;
            v[0] = *(const unsigned long long*)p0;
            v[1] = *(const unsigned long long*)(p0 + 1032);
            *(u64x2*)(dst + (size_t)s * 16) = v;
        }
        return;
    }

    if (blk < 8320) {
        // ---- input pack + verbatim copies (no zero-init needed: zero-skip
        //      flags in the t=1 cells make hbuf/cst write-before-read) ----
        int i = (blk - 8192) * 256 + tid;       // 0..32767
        int b = i >> 11, l = i & 2047;
        f32x4 v1 = ((const f32x4*)x1)[i];
        f32x4 v2 = ((const f32x4*)x2)[i];
        int p = apos(b, l);
        uint32_t q1 = f4_to_fp8x4(v1[0], v1[1], v1[2], v1[3]);
        uint32_t q2 = f4_to_fp8x4(v2[0], v2[1], v2[2], v2[3]);
#pragma unroll
        for (int s = 0; s < 4; ++s) {
            xc1[s * 32768 + p] = (uint8_t)(q1 >> (8 * s));
            xc2[s * 32768 + p] = (uint8_t)(q2 >> (8 * s));
        }
        ((f32x4*)(out + 131072))[i]     = v1;   // x1_parts[0] == x1
        ((f32x4*)(out + 6 * 131072))[i] = v2;   // x2_parts[2] == x2
        return;
    }

    // ---- conv-weight pack, half-tiles: (mt, h) from 64 blocks ----
    short* lb16 = (short*)lbuf;                 // [16][520] shorts
    const int mt2 = blk - 8320;                 // 0..63
    const int mt = mt2 >> 1, h = mt2 & 1;
#pragma unroll 4
    for (int it = 0; it < 8; ++it) {
        int s  = it * 256 + tid;                // 0..2047
        int rl = s >> 7;
        int c0 = (s & 127) * 4;                 // 0..508
        f32x4 v = *(const f32x4*)(Wc + (size_t)(mt * 16 + rl) * 1024 + h * 512 + c0);
        short4v o;
        o[0] = f2bf(v[0]); o[1] = f2bf(v[1]); o[2] = f2bf(v[2]); o[3] = f2bf(v[3]);
        *(short4v*)(lb16 + rl * 520 + c0) = o;
    }
    __syncthreads();
    short* dst = Wcp + (size_t)mt * 16384 + h * 8192;
#pragma unroll 4
    for (int it = 0; it < 8; ++it) {
        int s    = it * 256 + tid;              // 0..2047, 4 shorts each
        int fl   = s >> 7;
        int w    = s & 127;
        int lane = w >> 1;
        int j0   = (s & 1) * 4;
        int rl   = lane & 15;
        int c0   = fl * 32 + (lane >> 4) * 8 + j0;
        *(short4v*)(dst + (size_t)s * 4) = *(const short4v*)(lb16 + rl * 520 + c0);
    }
}

// ---------------------------------------------------------------------------
// LSTM cell (fp8), both branches. Dual-job: blocks [0,512)=jA, [512,1024)=jB.
// Block owns 4 channels; 8 waves split K (4x Wih quarters, 4x Whh quarters).
// zf bit0: h_in == 0 -> Whh waves (w>=4) skip loads+MFMAs (exact zeros).
// zf bit1: c == 0 -> skip cst read.
// ---------------------------------------------------------------------------
struct CellJob {
    const uint8_t *Wih, *Whh;      // packed fp8 [512][64][512B]
    const float *bih, *bhh;        // [8192] fp32
    const uint8_t *xA, *xB, *hin;  // packed fp8 acts (hin: 2 branches x 32768B)
    float *cst;                    // [2][16][2048] fp32 in-place
    uint8_t *hout;                 // packed fp8 [2][32768]
    float *svA, *svB;              // optional fp32 [16][2048]
    short *midp;                   // optional bf16 conv-B fragments
    int slot;
    int zf;
};

__global__ __launch_bounds__(512, 4) void k_cell(CellJob jA, CellJob jB)
{
    __shared__ float gpart[8][2][16][17];

    const CellJob& J = (blockIdx.x < 512) ? jA : jB;
    const int bt   = blockIdx.x & 511;
    const int tid  = threadIdx.x;
    const int w    = tid >> 6;
    const int lane = tid & 63;
    const int r    = lane & 15;
    const int g4   = lane >> 4;
    const int kq   = w & 3;

    f32x4 accA = {0.f, 0.f, 0.f, 0.f};
    f32x4 accB = {0.f, 0.f, 0.f, 0.f};

    const bool skip = (J.zf & 1) && (w >= 4);
    if (!skip) {
        const uint8_t* Wsrc = (w < 4) ? J.Wih : J.Whh;
        const uint8_t* uA   = (w < 4) ? J.xA : J.hin;
        const uint8_t* uB   = (w < 4) ? J.xB : (J.hin + 32768);

        const uint8_t* wp = Wsrc + (((size_t)bt * 64 + kq * 16) << 9) + lane * 8;
        const uint8_t* ap = uA + ((kq * 16) << 9) + lane * 8;
        const uint8_t* bp = uB + ((kq * 16) << 9) + lane * 8;

        long wreg[16];
#pragma unroll
        for (int i = 0; i < 16; ++i)
            wreg[i] = *(const long*)(wp + ((size_t)i << 9));

#pragma unroll
        for (int i = 0; i < 16; ++i) {
            long av = *(const long*)(ap + ((size_t)i << 9));
            long bv = *(const long*)(bp + ((size_t)i << 9));
            accA = __builtin_amdgcn_mfma_f32_16x16x32_fp8_fp8(wreg[i], av, accA, 0, 0, 0);
            accB = __builtin_amdgcn_mfma_f32_16x16x32_fp8_fp8(wreg[i], bv, accB, 0, 0, 0);
        }
    }

    // C layout: col = lane&15, row m = g4*4+q  (m -> gate m>>2, chl m&3)
#pragma unroll
    for (int q = 0; q < 4; ++q) {
        gpart[w][0][g4 * 4 + q][r] = accA[q];
        gpart[w][1][g4 * 4 + q][r] = accB[q];
    }
    __syncthreads();

    if (tid < 128) {
        const int br  = tid >> 6;
        const int chl = (tid >> 4) & 3;
        const int n   = tid & 15;

        float gi = 0.f, gf = 0.f, gg = 0.f, go = 0.f;
#pragma unroll
        for (int ww = 0; ww < 8; ++ww) {
            gi += gpart[ww][br][chl][n];
            gf += gpart[ww][br][4 + chl][n];
            gg += gpart[ww][br][8 + chl][n];
            go += gpart[ww][br][12 + chl][n];
        }
        const int ch = bt * 4 + chl;
        gi = gi * INVWS + J.bih[ch]            + J.bhh[ch];
        gf = gf * INVWS + J.bih[2048 + ch]     + J.bhh[2048 + ch];
        gg = gg * INVWS + J.bih[2 * 2048 + ch] + J.bhh[2 * 2048 + ch];
        go = go * INVWS + J.bih[3 * 2048 + ch] + J.bhh[3 * 2048 + ch];

        const size_t idx = ((size_t)br * NBATCH + n) * 2048 + ch;
        float cold = (J.zf & 2) ? 0.f : J.cst[idx];
        float cn = sigmoidf_(gf) * cold + sigmoidf_(gi) * tanhf(gg);
        float hn = sigmoidf_(go) * tanhf(cn);
        J.cst[idx] = cn;
        J.hout[br * 32768 + apos(n, ch)] = f2fp8hw(hn);
        if (br == 0) { if (J.svA) J.svA[(size_t)n * 2048 + ch] = hn; }
        else         { if (J.svB) J.svB[(size_t)n * 2048 + ch] = hn; }
        if (J.midp) {
            int i8, pos;
            if (br == 0) { i8 = ch >> 2;         pos = n * 16 + (ch & 3) * 4 + J.slot; }
            else         { i8 = 512 + (ch >> 2); pos = n * 16 + (ch & 3) * 4 + (3 - J.slot); }
            J.midp[(pos >> 4) * 16384 + (i8 >> 5) * 512
                   + (((i8 >> 3) & 3) * 16 + (pos & 15)) * 8 + (i8 & 7)] = f2bf(hn);
        }
    }
}

// ---------------------------------------------------------------------------
// Finish (merged): blocks [0,256) = out[2..5] scatter (coalesced both sides);
// blocks [256,768) = 1x1 conv as packed MFMA GEMM (mt,nt), 4 waves on K=1024.
// out2=[de1,p1,p2,p3]=SA[w]; out3=SA[4+w]; out4=SB[7-w]; out5=SB[3-w]
// ---------------------------------------------------------------------------
__global__ __launch_bounds__(512) void k_fin2(
    const short* __restrict__ Wcp, const short* __restrict__ midp,
    const float* __restrict__ bc,
    const float* __restrict__ SA, const float* __restrict__ SB,
    float* __restrict__ out)
{
    __shared__ float gp[4][16][17];
    const int tid = threadIdx.x;

    if (blockIdx.x < 256) {
        int i  = blockIdx.x * 512 + tid;       // 0..131071
        int q  = i >> 15;
        int rr = i & 32767;
        const float* base = (q < 2) ? SA : SB;
        int sl0 = (q == 0) ? 0 : (q == 1) ? 4 : (q == 2) ? 7 : 3;
        int stp = (q < 2) ? 1 : -1;
        f32x4 o;
#pragma unroll
        for (int w2 = 0; w2 < 4; ++w2)
            o[w2] = base[(size_t)(sl0 + stp * w2) * 32768 + rr];
        ((f32x4*)(out + (size_t)(2 + q) * 131072))[rr] = o;
        return;
    }

    const int blk2 = blockIdx.x - 256;         // 0..511
    const int mt = blk2 >> 4, nt = blk2 & 15;
    if (tid < 256) {
        const int kw = tid >> 6, lane = tid & 63;
        const short* ap = Wcp + (size_t)mt * 16384 + kw * 8 * 512 + lane * 8;
        const short* bp = midp + (size_t)nt * 16384 + kw * 8 * 512 + lane * 8;
        f32x4 acc = {0.f, 0.f, 0.f, 0.f};
#pragma unroll
        for (int i = 0; i < 8; ++i) {
            short8 a = *(const short8*)(ap + i * 512);
            short8 b = *(const short8*)(bp + i * 512);
            acc = __builtin_amdgcn_mfma_f32_16x16x32_bf16(a, b, acc, 0, 0, 0);
        }
        const int r = lane & 15, g4 = lane >> 4;
#pragma unroll
        for (int q = 0; q < 4; ++q) gp[kw][g4 * 4 + q][r] = acc[q];
    }
    __syncthreads();
    if (tid < 256) {
        const int m = tid >> 4, nl = tid & 15;
        float s = gp[0][m][nl] + gp[1][m][nl] + gp[2][m][nl] + gp[3][m][nl];
        const int o = mt * 16 + m, pos = nt * 16 + nl;
        s += bc[o];
        s = s > 0.f ? s : 0.2f * s;
        const int b = pos >> 4, hp = (pos >> 2) & 3, w = pos & 3;
        out[(size_t)b * 8192 + o * 16 + hp * 4 + w] = s;
    }
}

__global__ void k_wsfail(float* out) { if (threadIdx.x == 0 && blockIdx.x == 0) out[0] = -7.7e7f; }

// ---------------------------------------------------------------------------
extern "C" void kernel_launch(void* const* d_in, const int* in_sizes, int n_in,
                              void* d_out, int out_size, void* d_ws, size_t ws_size,
                              hipStream_t stream)
{
    const float* x1      = (const float*)d_in[0];
    const float* x2      = (const float*)d_in[1];
    const float* enc_Wih = (const float*)d_in[2];
    const float* enc_Whh = (const float*)d_in[3];
    const float* enc_bih = (const float*)d_in[4];
    const float* enc_bhh = (const float*)d_in[5];
    const float* dec_Wih = (const float*)d_in[6];
    const float* dec_Whh = (const float*)d_in[7];
    const float* dec_bih = (const float*)d_in[8];
    const float* dec_bhh = (const float*)d_in[9];
    const float* conv_W  = (const float*)d_in[10];
    const float* conv_b  = (const float*)d_in[11];
    float* out = (float*)d_out;

    // workspace (mats 0..3 = enc{ihL0,ihL1,hhL0,hhL1}, 4..7 = dec)
    uint8_t* Wb   = (uint8_t*)d_ws;            // 8 * MAT_B fp8
    uint8_t* xc1  = Wb + 8 * MAT_B;            // 4 chunks * 32768 B
    uint8_t* xc2  = xc1 + 131072;
    uint8_t* hbuf = xc2 + 131072;              // [2][2][2][32768] fp8
    float*   cst  = (float*)(hbuf + 262144);   // [2][2][16][2048] fp32
    float*   SA   = cst + 131072;              // 8 slots * 32768 fp32
    float*   SB   = SA + 262144;
    short*   midp = (short*)(SB + 262144);     // 16 nt * 16384 bf16
    short*   Wcp  = midp + 262144;             // 32 mt * 16384 bf16
    size_t need = (size_t)((char*)(Wcp + 524288) - (char*)d_ws);
    if (ws_size < need) { k_wsfail<<<1, 64, 0, stream>>>(out); return; }

    k_pack8i<<<8384, 256, 0, stream>>>(enc_Wih, enc_Whh, dec_Wih, dec_Whh, Wb,
                                       x1, x2, xc1, xc2, conv_W, Wcp, out);

    auto hB = [&](int layer, int par) -> uint8_t* {
        return hbuf + layer * 131072 + par * 65536;
    };

    auto mkJob = [&](int t, int layer) -> CellJob {
        const bool enc = (t <= 4);
        CellJob j;
        int base = enc ? 0 : 4;
        j.Wih = Wb + (size_t)(base + layer) * MAT_B;
        j.Whh = Wb + (size_t)(base + 2 + layer) * MAT_B;
        j.bih = (enc ? enc_bih : dec_bih) + layer * 8192;
        j.bhh = (enc ? enc_bhh : dec_bhh) + layer * 8192;
        j.zf = (t == 1) ? 3 : 0;               // t=1: h_in==0 and c==0 (both layers)
        if (layer == 0) {
            if (t <= 4)      { j.xA = xc2 + (size_t)(t - 1) * 32768; j.xB = xc1 + (size_t)(4 - t) * 32768; }
            else if (t <= 8) { j.xA = xc1 + (size_t)(t - 5) * 32768; j.xB = xc2 + (size_t)(8 - t) * 32768; }
            else             { const uint8_t* hp = hB(1, (t - 1) & 1); j.xA = hp; j.xB = hp + 32768; }
            j.hin = hB(0, (t - 1) & 1);
            j.cst = cst;
            j.hout = hB(0, t & 1);
            j.svA = nullptr; j.svB = nullptr; j.midp = nullptr; j.slot = 0;
        } else {
            const uint8_t* hx = hB(0, t & 1);
            j.xA = hx; j.xB = hx + 32768;
            j.hin = hB(1, (t - 1) & 1);
            j.cst = cst + 65536;
            j.hout = hB(1, t & 1);
            j.svA = (t >= 8) ? SA + (size_t)(t - 8) * 32768 : nullptr;
            j.svB = (t >= 8) ? SB + (size_t)(t - 8) * 32768 : nullptr;
            j.midp = (t >= 8 && t <= 11) ? midp : nullptr;
            j.slot = (t >= 8) ? (t - 8) : 0;
        }
        return j;
    };

    // t=1 layer0 alone (zf=3: skips Whh + cst read; exact-zero contributions)
    k_cell<<<512, 512, 0, stream>>>(mkJob(1, 0), mkJob(1, 0));
    // t=2..8: layer0(t) || layer1(t-1)  (independent; L1(1) has zf=3)
    for (int t = 2; t <= 8; ++t)
        k_cell<<<1024, 512, 0, stream>>>(mkJob(t, 0), mkJob(t - 1, 1));
    // layer1(8) alone
    k_cell<<<512, 512, 0, stream>>>(mkJob(8, 1), mkJob(8, 1));
    // AR steps: strictly serial
    for (int t = 9; t <= 15; ++t) {
        k_cell<<<512, 512, 0, stream>>>(mkJob(t, 0), mkJob(t, 0));
        k_cell<<<512, 512, 0, stream>>>(mkJob(t, 1), mkJob(t, 1));
    }

    k_fin2<<<768, 512, 0, stream>>>(Wcp, midp, conv_b, SA, SB, out);
}

// Round 10
// 364.472 us; speedup vs baseline: 3.3525x; 1.0034x over previous
//
#include <hip/hip_runtime.h>
#include <cstdint>
#include <cstddef>

// ---------------------------------------------------------------------------
// Sizes: C=512,H=4,W=4,SPLIT=4,WC=1 -> L=2048, B=16, gates=4*L=8192
// 8 weight matrices of [8192][2048] fp32 -> fp8 e4m3 (x64 scale), packed as
// 512 ch-tiles x 64 k-steps, each a 16x32 fragment in MFMA lane order
// (lane l holds 8 bytes at frag*512 + l*8).
// Fragment map: A-row r -> weight row (r>>2)*2048 + bt*4 + (r&3);
//               k = ks*32 + (l>>4)*8 + j.
// Activations: same per-fragment packing (fp8, unscaled), col = batch n.
// Gate epilogue multiplies the MFMA sum by 1/64.
// fp8 quantize uses HW v_cvt_pk_fp8_f32 (OCP e4m3fn on gfx950, RNE+sat).
// Round 7 lesson: persistent kernel + device barriers = 3.2x regression.
// Round 10: deeper load pipelining in cells (16KB in flight/wave); decoder
// L1 cells write out[2..5] directly (SA/SB + scatter pass removed); fin is
// conv-only.
// ---------------------------------------------------------------------------

typedef __attribute__((ext_vector_type(8))) short short8;   // 8 x bf16
typedef __attribute__((ext_vector_type(4))) short short4v;
typedef __attribute__((ext_vector_type(4))) float f32x4;
typedef __attribute__((ext_vector_type(2))) unsigned long long u64x2;

#define NBATCH 16
#define MAT_B   16777216ull     // bytes per packed fp8 matrix (8192*2048)
#define WSCALE  64.0f
#define INVWS   (1.0f / 64.0f)

__device__ __forceinline__ short f2bf(float f) {
    union { float f; unsigned u; } c; c.f = f;
    unsigned u = c.u;
    unsigned r = (u + 0x7FFFu + ((u >> 16) & 1u)) >> 16;
    return (short)r;
}

// HW packed fp8 quantize: 4 floats -> 4 OCP e4m3fn bytes (one dword)
__device__ __forceinline__ uint32_t f4_to_fp8x4(float a, float b, float c, float d) {
    int p = __builtin_amdgcn_cvt_pk_fp8_f32(a, b, 0, false);   // bytes 0,1
    p = __builtin_amdgcn_cvt_pk_fp8_f32(c, d, p, true);        // bytes 2,3
    return (uint32_t)p;
}

__device__ __forceinline__ uint8_t f2fp8hw(float x) {
    return (uint8_t)(__builtin_amdgcn_cvt_pk_fp8_f32(x, x, 0, false) & 0xFF);
}

__device__ __forceinline__ float sigmoidf_(float x) { return 1.f / (1.f + __expf(-x)); }

// packed byte offset for activation element (batch n, feature k)
__device__ __forceinline__ int apos(int n, int k) {
    return ((k >> 5) << 9) + ((((k >> 3) & 3) << 4) + n) * 8 + (k & 7);
}

// ---------------------------------------------------------------------------
// Merged prep dispatch, grid 8384:
//   blocks [0,8192):    pack 8 weight matrices fp32 -> fragment fp8 (x64)
//   blocks [8192,8320): input pack (fp8) + verbatim copies x1->out1, x2->out6
//   blocks [8320,8384): conv-weight pack fp32 -> bf16 fragments (half-tiles)
// ---------------------------------------------------------------------------
__global__ __launch_bounds__(256) void k_pack8i(
    const float* __restrict__ enc_Wih, const float* __restrict__ enc_Whh,
    const float* __restrict__ dec_Wih, const float* __restrict__ dec_Whh,
    uint8_t* __restrict__ dstbase,
    const float* __restrict__ x1, const float* __restrict__ x2,
    uint8_t* __restrict__ xc1, uint8_t* __restrict__ xc2,
    const float* __restrict__ Wc, short* __restrict__ Wcp,
    float* __restrict__ out)
{
    __shared__ uint8_t lbuf[16 * 1040];         // 16.6 KB, shared by all roles
    const int blk = blockIdx.x;
    const int tid = threadIdx.x;

    if (blk < 8192) {
        // ---- weight pack: (om, bt, half); om 0..3 = dec first, enc last ----
        const int om   = blk >> 10;
        const int mat  = (om + 4) & 7;          // dec (4..7) first, enc (0..3) last
        const int sub  = blk & 1023;
        const int bt   = sub >> 1;
        const int half = sub & 1;

        const float* srcs[4] = { enc_Wih, enc_Whh, dec_Wih, dec_Whh };
        const float* src = srcs[mat >> 1] + (size_t)(mat & 1) * 16777216ull;
        uint8_t* dst = dstbase + (size_t)mat * MAT_B
                     + (((size_t)bt * 64 + half * 32) << 9);

        // phase 1: coalesced row reads -> fp8 LDS tile [16][1024] (+8 pad)
#pragma unroll 4
        for (int it = 0; it < 16; ++it) {
            int s  = it * 256 + tid;            // 0..4095
            int rl = s >> 8;
            int c0 = (s & 255) * 4;
            int row = (rl >> 2) * 2048 + bt * 4 + (rl & 3);
            f32x4 v = __builtin_nontemporal_load(
                (const f32x4*)(src + (size_t)row * 2048 + half * 1024 + c0));
            uint32_t w32 = f4_to_fp8x4(v[0] * WSCALE, v[1] * WSCALE,
                                       v[2] * WSCALE, v[3] * WSCALE);
            *(uint32_t*)(lbuf + rl * 1032 + c0) = w32;
        }
        __syncthreads();

        // phase 2: fragment-order linear writes, 16 B per thread-iter.
#pragma unroll
        for (int it = 0; it < 4; ++it) {
            int s  = it * 256 + tid;            // 0..1023
            int fl = s >> 5;
            int m  = s & 31;
            const uint8_t* p0 = lbuf + ((2 * m) & 15) * 1032 + fl * 32 + (m >> 3) * 8;
            u64x2 v;
            v[0] = *(const unsigned long long*)p0;
            v[1] = *(const unsigned long long*)(p0 + 1032);
            *(u64x2*)(dst + (size_t)s * 16) = v;
        }
        return;
    }

    if (blk < 8320) {
        // ---- input pack + verbatim copies (zero-skip flags in t=1 cells
        //      make hbuf/cst write-before-read; no zero-init pass) ----
        int i = (blk - 8192) * 256 + tid;       // 0..32767
        int b = i >> 11, l = i & 2047;
        f32x4 v1 = ((const f32x4*)x1)[i];
        f32x4 v2 = ((const f32x4*)x2)[i];
        int p = apos(b, l);
        uint32_t q1 = f4_to_fp8x4(v1[0], v1[1], v1[2], v1[3]);
        uint32_t q2 = f4_to_fp8x4(v2[0], v2[1], v2[2], v2[3]);
#pragma unroll
        for (int s = 0; s < 4; ++s) {
            xc1[s * 32768 + p] = (uint8_t)(q1 >> (8 * s));
            xc2[s * 32768 + p] = (uint8_t)(q2 >> (8 * s));
        }
        ((f32x4*)(out + 131072))[i]     = v1;   // x1_parts[0] == x1
        ((f32x4*)(out + 6 * 131072))[i] = v2;   // x2_parts[2] == x2
        return;
    }

    // ---- conv-weight pack, half-tiles: (mt, h) from 64 blocks ----
    short* lb16 = (short*)lbuf;                 // [16][520] shorts
    const int mt2 = blk - 8320;                 // 0..63
    const int mt = mt2 >> 1, h = mt2 & 1;
#pragma unroll 4
    for (int it = 0; it < 8; ++it) {
        int s  = it * 256 + tid;                // 0..2047
        int rl = s >> 7;
        int c0 = (s & 127) * 4;                 // 0..508
        f32x4 v = *(const f32x4*)(Wc + (size_t)(mt * 16 + rl) * 1024 + h * 512 + c0);
        short4v o;
        o[0] = f2bf(v[0]); o[1] = f2bf(v[1]); o[2] = f2bf(v[2]); o[3] = f2bf(v[3]);
        *(short4v*)(lb16 + rl * 520 + c0) = o;
    }
    __syncthreads();
    short* dst = Wcp + (size_t)mt * 16384 + h * 8192;
#pragma unroll 4
    for (int it = 0; it < 8; ++it) {
        int s    = it * 256 + tid;              // 0..2047, 4 shorts each
        int fl   = s >> 7;
        int w    = s & 127;
        int lane = w >> 1;
        int j0   = (s & 1) * 4;
        int rl   = lane & 15;
        int c0   = fl * 32 + (lane >> 4) * 8 + j0;
        *(short4v*)(dst + (size_t)s * 4) = *(const short4v*)(lb16 + rl * 520 + c0);
    }
}

// ---------------------------------------------------------------------------
// LSTM cell (fp8), both branches. Dual-job: blocks [0,512)=jA, [512,1024)=jB.
// Block owns 4 channels; 8 waves split K (4x Wih quarters, 4x Whh quarters).
// zf bit0: h_in == 0 -> Whh waves (w>=4) skip loads+MFMAs (exact zeros).
// zf bit1: c == 0 -> skip cst read.
// slot >= 0 (decoder L1, t>=8): epilogue writes out[2..5] directly.
// ---------------------------------------------------------------------------
struct CellJob {
    const uint8_t *Wih, *Whh;      // packed fp8 [512][64][512B]
    const float *bih, *bhh;        // [8192] fp32
    const uint8_t *xA, *xB, *hin;  // packed fp8 acts (hin: 2 branches x 32768B)
    float *cst;                    // [2][16][2048] fp32 in-place
    uint8_t *hout;                 // packed fp8 [2][32768]
    short *midp;                   // optional bf16 conv-B fragments (t=8..11)
    float *outp;                   // d_out base (for direct out[2..5] writes)
    int slot;                      // t-8 for decoder L1 cells, else -1
    int zf;
};

__global__ __launch_bounds__(512, 4) void k_cell(CellJob jA, CellJob jB)
{
    __shared__ float gpart[8][2][16][17];

    const CellJob& J = (blockIdx.x < 512) ? jA : jB;
    const int bt   = blockIdx.x & 511;
    const int tid  = threadIdx.x;
    const int w    = tid >> 6;
    const int lane = tid & 63;
    const int r    = lane & 15;
    const int g4   = lane >> 4;
    const int kq   = w & 3;

    f32x4 accA = {0.f, 0.f, 0.f, 0.f};
    f32x4 accB = {0.f, 0.f, 0.f, 0.f};

    const bool skip = (J.zf & 1) && (w >= 4);
    if (!skip) {
        const uint8_t* Wsrc = (w < 4) ? J.Wih : J.Whh;
        const uint8_t* uA   = (w < 4) ? J.xA : J.hin;
        const uint8_t* uB   = (w < 4) ? J.xB : (J.hin + 32768);

        const uint8_t* wp = Wsrc + (((size_t)bt * 64 + kq * 16) << 9) + lane * 8;
        const uint8_t* ap = uA + ((kq * 16) << 9) + lane * 8;
        const uint8_t* bp = uB + ((kq * 16) << 9) + lane * 8;

        long wreg[16];
#pragma unroll
        for (int i = 0; i < 16; ++i)
            wreg[i] = *(const long*)(wp + ((size_t)i << 9));

        // two halves: preload 8 av + 8 bv (16 KB in flight incl. wreg tail),
        // then 16 MFMAs; maximizes MLP during dispatch ramp.
#pragma unroll
        for (int half = 0; half < 2; ++half) {
            long av8[8], bv8[8];
#pragma unroll
            for (int i = 0; i < 8; ++i) {
                av8[i] = *(const long*)(ap + ((size_t)(half * 8 + i) << 9));
                bv8[i] = *(const long*)(bp + ((size_t)(half * 8 + i) << 9));
            }
#pragma unroll
            for (int i = 0; i < 8; ++i) {
                accA = __builtin_amdgcn_mfma_f32_16x16x32_fp8_fp8(wreg[half * 8 + i], av8[i], accA, 0, 0, 0);
                accB = __builtin_amdgcn_mfma_f32_16x16x32_fp8_fp8(wreg[half * 8 + i], bv8[i], accB, 0, 0, 0);
            }
        }
    }

    // C layout: col = lane&15, row m = g4*4+q  (m -> gate m>>2, chl m&3)
#pragma unroll
    for (int q = 0; q < 4; ++q) {
        gpart[w][0][g4 * 4 + q][r] = accA[q];
        gpart[w][1][g4 * 4 + q][r] = accB[q];
    }
    __syncthreads();

    if (tid < 128) {
        const int br  = tid >> 6;
        const int chl = (tid >> 4) & 3;
        const int n   = tid & 15;

        float gi = 0.f, gf = 0.f, gg = 0.f, go = 0.f;
#pragma unroll
        for (int ww = 0; ww < 8; ++ww) {
            gi += gpart[ww][br][chl][n];
            gf += gpart[ww][br][4 + chl][n];
            gg += gpart[ww][br][8 + chl][n];
            go += gpart[ww][br][12 + chl][n];
        }
        const int ch = bt * 4 + chl;
        gi = gi * INVWS + J.bih[ch]            + J.bhh[ch];
        gf = gf * INVWS + J.bih[2048 + ch]     + J.bhh[2048 + ch];
        gg = gg * INVWS + J.bih[2 * 2048 + ch] + J.bhh[2 * 2048 + ch];
        go = go * INVWS + J.bih[3 * 2048 + ch] + J.bhh[3 * 2048 + ch];

        const size_t idx = ((size_t)br * NBATCH + n) * 2048 + ch;
        float cold = (J.zf & 2) ? 0.f : J.cst[idx];
        float cn = sigmoidf_(gf) * cold + sigmoidf_(gi) * tanhf(gg);
        float hn = sigmoidf_(go) * tanhf(cn);
        J.cst[idx] = cn;
        J.hout[br * 32768 + apos(n, ch)] = f2fp8hw(hn);

        if (J.slot >= 0) {
            // direct out[2..5] write (inverse of verified scatter):
            // A: slot s<4 -> out2[.,s];  s>=4 -> out3[.,s-4]
            // B: s>=4 -> out4[.,7-s];    s<4  -> out5[.,3-s]
            const int s = J.slot;
            const size_t rr4 = (size_t)(n * 2048 + ch) * 4;
            int q, w2;
            if (br == 0) { if (s < 4) { q = 2; w2 = s; } else { q = 3; w2 = s - 4; } }
            else         { if (s >= 4) { q = 4; w2 = 7 - s; } else { q = 5; w2 = 3 - s; } }
            J.outp[(size_t)q * 131072 + rr4 + w2] = hn;
        }
        if (J.midp) {
            int i8, pos;
            if (br == 0) { i8 = ch >> 2;         pos = n * 16 + (ch & 3) * 4 + J.slot; }
            else         { i8 = 512 + (ch >> 2); pos = n * 16 + (ch & 3) * 4 + (3 - J.slot); }
            J.midp[(pos >> 4) * 16384 + (i8 >> 5) * 512
                   + (((i8 >> 3) & 3) * 16 + (pos & 15)) * 8 + (i8 & 7)] = f2bf(hn);
        }
    }
}

// ---------------------------------------------------------------------------
// 1x1 conv as packed MFMA GEMM: out0[512 x 256pos] = Wcp[512][1024] x midp
// grid 512 = (mt 0..31) x (nt 0..15); 4 waves split K=1024.
// ---------------------------------------------------------------------------
__global__ __launch_bounds__(256) void k_conv3(
    const short* __restrict__ Wcp, const short* __restrict__ midp,
    const float* __restrict__ bc, float* __restrict__ out)
{
    __shared__ float gp[4][16][17];
    const int mt = blockIdx.x >> 4, nt = blockIdx.x & 15;
    const int tid = threadIdx.x, kw = tid >> 6, lane = tid & 63;
    const short* ap = Wcp + (size_t)mt * 16384 + kw * 8 * 512 + lane * 8;
    const short* bp = midp + (size_t)nt * 16384 + kw * 8 * 512 + lane * 8;
    f32x4 acc = {0.f, 0.f, 0.f, 0.f};
#pragma unroll
    for (int i = 0; i < 8; ++i) {
        short8 a = *(const short8*)(ap + i * 512);
        short8 b = *(const short8*)(bp + i * 512);
        acc = __builtin_amdgcn_mfma_f32_16x16x32_bf16(a, b, acc, 0, 0, 0);
    }
    const int r = lane & 15, g4 = lane >> 4;
#pragma unroll
    for (int q = 0; q < 4; ++q) gp[kw][g4 * 4 + q][r] = acc[q];
    __syncthreads();

    const int m = tid >> 4, nl = tid & 15;
    float s = gp[0][m][nl] + gp[1][m][nl] + gp[2][m][nl] + gp[3][m][nl];
    const int o = mt * 16 + m, pos = nt * 16 + nl;
    s += bc[o];
    s = s > 0.f ? s : 0.2f * s;
    const int b = pos >> 4, hp = (pos >> 2) & 3, w = pos & 3;
    out[(size_t)b * 8192 + o * 16 + hp * 4 + w] = s;
}

__global__ void k_wsfail(float* out) { if (threadIdx.x == 0 && blockIdx.x == 0) out[0] = -7.7e7f; }

// ---------------------------------------------------------------------------
extern "C" void kernel_launch(void* const* d_in, const int* in_sizes, int n_in,
                              void* d_out, int out_size, void* d_ws, size_t ws_size,
                              hipStream_t stream)
{
    const float* x1      = (const float*)d_in[0];
    const float* x2      = (const float*)d_in[1];
    const float* enc_Wih = (const float*)d_in[2];
    const float* enc_Whh = (const float*)d_in[3];
    const float* enc_bih = (const float*)d_in[4];
    const float* enc_bhh = (const float*)d_in[5];
    const float* dec_Wih = (const float*)d_in[6];
    const float* dec_Whh = (const float*)d_in[7];
    const float* dec_bih = (const float*)d_in[8];
    const float* dec_bhh = (const float*)d_in[9];
    const float* conv_W  = (const float*)d_in[10];
    const float* conv_b  = (const float*)d_in[11];
    float* out = (float*)d_out;

    // workspace (mats 0..3 = enc{ihL0,ihL1,hhL0,hhL1}, 4..7 = dec)
    uint8_t* Wb   = (uint8_t*)d_ws;            // 8 * MAT_B fp8
    uint8_t* xc1  = Wb + 8 * MAT_B;            // 4 chunks * 32768 B
    uint8_t* xc2  = xc1 + 131072;
    uint8_t* hbuf = xc2 + 131072;              // [2][2][2][32768] fp8
    float*   cst  = (float*)(hbuf + 262144);   // [2][2][16][2048] fp32
    short*   midp = (short*)(cst + 131072);    // 16 nt * 16384 bf16
    short*   Wcp  = midp + 262144;             // 32 mt * 16384 bf16
    size_t need = (size_t)((char*)(Wcp + 524288) - (char*)d_ws);
    if (ws_size < need) { k_wsfail<<<1, 64, 0, stream>>>(out); return; }

    k_pack8i<<<8384, 256, 0, stream>>>(enc_Wih, enc_Whh, dec_Wih, dec_Whh, Wb,
                                       x1, x2, xc1, xc2, conv_W, Wcp, out);

    auto hB = [&](int layer, int par) -> uint8_t* {
        return hbuf + layer * 131072 + par * 65536;
    };

    auto mkJob = [&](int t, int layer) -> CellJob {
        const bool enc = (t <= 4);
        CellJob j;
        int base = enc ? 0 : 4;
        j.Wih = Wb + (size_t)(base + layer) * MAT_B;
        j.Whh = Wb + (size_t)(base + 2 + layer) * MAT_B;
        j.bih = (enc ? enc_bih : dec_bih) + layer * 8192;
        j.bhh = (enc ? enc_bhh : dec_bhh) + layer * 8192;
        j.zf = (t == 1) ? 3 : 0;               // t=1: h_in==0 and c==0 (both layers)
        j.outp = out;
        if (layer == 0) {
            if (t <= 4)      { j.xA = xc2 + (size_t)(t - 1) * 32768; j.xB = xc1 + (size_t)(4 - t) * 32768; }
            else if (t <= 8) { j.xA = xc1 + (size_t)(t - 5) * 32768; j.xB = xc2 + (size_t)(8 - t) * 32768; }
            else             { const uint8_t* hp = hB(1, (t - 1) & 1); j.xA = hp; j.xB = hp + 32768; }
            j.hin = hB(0, (t - 1) & 1);
            j.cst = cst;
            j.hout = hB(0, t & 1);
            j.midp = nullptr; j.slot = -1;
        } else {
            const uint8_t* hx = hB(0, t & 1);
            j.xA = hx; j.xB = hx + 32768;
            j.hin = hB(1, (t - 1) & 1);
            j.cst = cst + 65536;
            j.hout = hB(1, t & 1);
            j.midp = (t >= 8 && t <= 11) ? midp : nullptr;
            j.slot = (t >= 8) ? (t - 8) : -1;
        }
        return j;
    };

    // t=1 layer0 alone (zf=3: skips Whh + cst read; exact-zero contributions)
    k_cell<<<512, 512, 0, stream>>>(mkJob(1, 0), mkJob(1, 0));
    // t=2..8: layer0(t) || layer1(t-1)  (independent; L1(1) has zf=3)
    for (int t = 2; t <= 8; ++t)
        k_cell<<<1024, 512, 0, stream>>>(mkJob(t, 0), mkJob(t - 1, 1));
    // layer1(8) alone
    k_cell<<<512, 512, 0, stream>>>(mkJob(8, 1), mkJob(8, 1));
    // AR steps: strictly serial
    for (int t = 9; t <= 15; ++t) {
        k_cell<<<512, 512, 0, stream>>>(mkJob(t, 0), mkJob(t, 0));
        k_cell<<<512, 512, 0, stream>>>(mkJob(t, 1), mkJob(t, 1));
    }

    k_conv3<<<512, 256, 0, stream>>>(Wcp, midp, conv_b, out);
}